// Round 1
// baseline (249.561 us; speedup 1.0000x reference)
//
#include <hip/hip_runtime.h>
#include <hip/hip_bf16.h>
#include <math.h>

typedef __bf16 bf16;
typedef _Float16 f16;
typedef __attribute__((ext_vector_type(8))) __bf16 bf16x8;
typedef __attribute__((ext_vector_type(8))) _Float16 f16x8;
typedef __attribute__((ext_vector_type(4))) _Float16 f16x4;
typedef __attribute__((ext_vector_type(4))) float floatx4;

__device__ __forceinline__ void split8(floatx4 a0, floatx4 a1, bf16x8& hi, bf16x8& lo) {
#pragma unroll
    for (int t = 0; t < 4; t++) {
        float v0 = a0[t], v1 = a1[t];
        bf16 h0 = (bf16)v0, h1 = (bf16)v1;
        hi[t] = h0;     lo[t] = (bf16)(v0 - (float)h0);
        hi[t + 4] = h1; lo[t + 4] = (bf16)(v1 - (float)h1);
    }
}

// ---------------- projection: qkv = hs @ Wqkv^T + bqkv (fp32-accurate via bf16 hi/lo split) ----------------
// blocks 0..383: one 16x16 tile per wave -> q f16 [b*s][r], k f16 [b*l][r], vT f16 [b][p][l]
// blocks 384..447: Wc fp32 -> f16 copy (for the attn B-frag build)
__global__ __launch_bounds__(256, 4)
void proj_kernel(const float* __restrict__ hs, const float* __restrict__ Wq,
                 const float* __restrict__ bq, const float* __restrict__ Wc,
                 f16* __restrict__ q_ws, f16* __restrict__ k_ws,
                 f16* __restrict__ vT_ws, f16* __restrict__ Wc_ws)
{
    const int tid = threadIdx.x;
    if (blockIdx.x >= 384) {           // Wc fp32 -> f16
        const int base = (blockIdx.x - 384) * 1024 + tid * 4;
        floatx4 w = *(const floatx4*)(Wc + base);
        f16x4 h;
        h.x = (f16)w.x; h.y = (f16)w.y; h.z = (f16)w.z; h.w = (f16)w.w;
        *(f16x4*)(Wc_ws + base) = h;
        return;
    }
    const int wv = tid >> 6, lane = tid & 63;
    const int quad = lane >> 4, lcol = lane & 15;
    const int wt = blockIdx.x * 4 + wv;          // 0..1535: 32 row-tiles x 48 col-tiles
    const int rt = wt / 48, ct = wt - rt * 48;
    const int row0 = rt * 16, col0 = ct * 16;

    const float* arow = hs + (row0 + lcol) * 256;   // A: m = lcol (bs-row)
    const float* brow = Wq + (col0 + lcol) * 256;   // B: n = lcol (out-col), torch [out,in]

    floatx4 acc = {0.f, 0.f, 0.f, 0.f};
#pragma unroll
    for (int ks = 0; ks < 8; ks++) {
        const int h = ks * 32 + quad * 8;
        floatx4 a0 = *(const floatx4*)(arow + h);
        floatx4 a1 = *(const floatx4*)(arow + h + 4);
        floatx4 b0 = *(const floatx4*)(brow + h);
        floatx4 b1 = *(const floatx4*)(brow + h + 4);
        bf16x8 ahi, alo, bhi, blo;
        split8(a0, a1, ahi, alo);
        split8(b0, b1, bhi, blo);
        acc = __builtin_amdgcn_mfma_f32_16x16x32_bf16(ahi, bhi, acc, 0, 0, 0);
        acc = __builtin_amdgcn_mfma_f32_16x16x32_bf16(ahi, blo, acc, 0, 0, 0);
        acc = __builtin_amdgcn_mfma_f32_16x16x32_bf16(alo, bhi, acc, 0, 0, 0);
    }
    const float bias = bq[col0 + lcol];
    const int col = col0 + lcol, seg = col0 >> 8, jj = col & 255;
#pragma unroll
    for (int r = 0; r < 4; r++) {                   // C: row = quad*4 + r, col = lcol
        const int row = row0 + quad * 4 + r;
        const float val = acc[r] + bias;
        if (seg == 0)      q_ws[row * 256 + jj] = (f16)val;
        else if (seg == 1) k_ws[row * 256 + jj] = (f16)val;
        else               vT_ws[(row >> 8) * 65536 + jj * 256 + (row & 255)] = (f16)val;
    }
}

// ---------------- fused scores + softmax(l) + PV, v2: occupancy-first ----------------
// grid 512 = b(2) x sg(64: 4 s each) x pt(4: 64 p each). 512 thr = 8 waves = 2 s-halves x 4 l-quarters.
// LDS: ONLY Wc tile (32 KB, XOR-swizzled) + 8 KB merge buffers => ~41 KB => 2 blocks/CU (16 waves/CU,
// VGPR capped at 128 via __launch_bounds__(512,4)). K fragments read straight from global: K is 256 KB
// f16 total, L2-resident; per (i,kk) a wave touches 16 distinct 64B lines.
// scores D[m=l, n=p]: A-frag = K (global), B-frag = q*Wc built in registers (pk_mul). No barriers in
// the main loop. P = exp(scores) in f32 (scores ~ N(0,1); bc cancels in softmax over l).
// PV + denominator fully in registers: acc already holds P at (l = i*16+quad*4+t, p = j*16+lcol) and
// vT is [p][l], so osum/ssum are per-lane FMAs + a 2-step shfl_xor(16,32) butterfly over the quad bits.
// Cross-wave (lq) merge once at the end through 8 KB LDS. Barriers per block: 2 (was 9).
__global__ __launch_bounds__(512, 4)
void attn_main(const f16* __restrict__ qw, const f16* __restrict__ kw,
               const f16* __restrict__ vT, const f16* __restrict__ Wc16,
               float* __restrict__ out)
{
    __shared__ f16 Wlds[64 * 256];      // 32768 B, XOR-swizzled (chunk c stores global chunk c^(row&7))
    __shared__ float obuf[4][4][64];    //  4096 B: [lq][s-slot][p]
    __shared__ float sbuf[4][4][64];    //  4096 B

    const int bid = blockIdx.x;
    const int pt = bid & 3;
    const int sg = (bid >> 2) & 63;
    const int b  = bid >> 8;
    const int p0 = pt * 64;
    const int tid  = threadIdx.x;
    const int wv   = tid >> 6;
    const int lane = tid & 63;
    const int quad = lane >> 4, lcol = lane & 15;
    const int lq = wv & 3, sh = wv >> 2;
    const int l0w = lq * 64;

    const f16* kbase = kw + b * 65536;
    const f16* vbase = vT + b * 65536;

    // ---- stage Wc tile [64 p][256 r] once, swizzled: 2048 16-B chunks / 512 thr = 4 iters ----
#pragma unroll
    for (int it = 0; it < 4; it++) {
        const int id = tid + it * 512;
        const int r = id >> 5, c = id & 31;
        const int csrc = c ^ (r & 7);
        uint4 d = *(const uint4*)(Wc16 + (p0 + r) * 256 + csrc * 8);
        *(uint4*)(Wlds + r * 256 + c * 8) = d;
    }
    __syncthreads();

    float osum[2][4], ssum[2][4];

#pragma unroll
    for (int sl = 0; sl < 2; sl++) {
        const int s = sg * 4 + sh * 2 + sl;
        const f16* qrow = qw + (b * 256 + s) * 256;

        floatx4 acc[4][4];
#pragma unroll
        for (int i = 0; i < 4; i++)
#pragma unroll
            for (int j = 0; j < 4; j++)
                acc[i][j] = (floatx4){0.f, 0.f, 0.f, 0.f};

#pragma unroll
        for (int kk = 0; kk < 8; kk++) {
            const int rb = kk * 32 + quad * 8;
            f16x8 qv = *(const f16x8*)(qrow + rb);
            f16x8 kf[4];
#pragma unroll
            for (int i = 0; i < 4; i++)    // A-frag from GLOBAL (L2-hot): m = lcol -> l-row
                kf[i] = *(const f16x8*)(kbase + (l0w + i * 16 + lcol) * 256 + rb);
#pragma unroll
            for (int j = 0; j < 4; j++) {  // B-frag: n = lcol -> p-row; built in regs (pk_mul)
                f16x8 w8 = *(const f16x8*)(Wlds + (j * 16 + lcol) * 256 +
                                           (((kk * 4 + quad) ^ (lcol & 7)) << 3));
                f16x8 bfr = w8 * qv;
#pragma unroll
                for (int i = 0; i < 4; i++)
                    acc[i][j] = __builtin_amdgcn_mfma_f32_16x16x32_f16(kf[i], bfr, acc[i][j], 0, 0, 0);
            }
        }

        // ---- in-register epilogue: P = exp(acc) in f32; osum/ssum per-lane, butterfly over quad ----
        float os[4] = {0.f, 0.f, 0.f, 0.f}, ss[4] = {0.f, 0.f, 0.f, 0.f};
#pragma unroll
        for (int i = 0; i < 4; i++) {
#pragma unroll
            for (int j = 0; j < 4; j++) {
                // v at (l = l0w+i*16+quad*4+t, p = p0+j*16+lcol): f16x4 contiguous in l
                f16x4 vf = *(const f16x4*)(vbase + (p0 + j * 16 + lcol) * 256 + l0w + i * 16 + quad * 4);
#pragma unroll
                for (int t = 0; t < 4; t++) {
                    const float P = __expf(acc[i][j][t]);
                    os[j] = fmaf(P, (float)vf[t], os[j]);
                    ss[j] += P;
                }
            }
        }
#pragma unroll
        for (int j = 0; j < 4; j++) {      // sum the 4 quad groups (lanes ^16, ^32)
            os[j] += __shfl_xor(os[j], 16);
            os[j] += __shfl_xor(os[j], 32);
            ss[j] += __shfl_xor(ss[j], 16);
            ss[j] += __shfl_xor(ss[j], 32);
            osum[sl][j] = os[j];
            ssum[sl][j] = ss[j];
        }
    }

    // ---- single cross-wave merge over lq ----
    if (quad == 0) {
#pragma unroll
        for (int sl = 0; sl < 2; sl++)
#pragma unroll
            for (int j = 0; j < 4; j++) {
                obuf[lq][sh * 2 + sl][j * 16 + lcol] = osum[sl][j];
                sbuf[lq][sh * 2 + sl][j * 16 + lcol] = ssum[sl][j];
            }
    }
    __syncthreads();

    if (tid < 256) {
        const int slot = tid >> 6, p = tid & 63;
        const float O = obuf[0][slot][p] + obuf[1][slot][p] + obuf[2][slot][p] + obuf[3][slot][p];
        const float S = sbuf[0][slot][p] + sbuf[1][slot][p] + sbuf[2][slot][p] + sbuf[3][slot][p];
        out[(b * 256 + sg * 4 + slot) * 256 + p0 + p] = O / S;
    }
}

extern "C" void kernel_launch(void* const* d_in, const int* in_sizes, int n_in,
                              void* d_out, int out_size, void* d_ws, size_t ws_size,
                              hipStream_t stream) {
    const float* hs   = (const float*)d_in[0];  // [2,256,256]
    const float* Wqkv = (const float*)d_in[1];  // [768,256]
    const float* bqkv = (const float*)d_in[2];  // [768]
    const float* Wc   = (const float*)d_in[3];  // [256,256]
    // d_in[4] (bc) cancels in softmax over l -> unused.
    float* out = (float*)d_out;

    char* ws = (char*)d_ws;
    f16* q_ws   = (f16*)ws;                      // 256 KB f16 q   [b*s][r]
    f16* k_ws   = (f16*)(ws + 262144);           // 256 KB f16 k   [b*l][r]
    f16* vT_ws  = (f16*)(ws + 524288);           // 256 KB f16 vT  [b][p][l]
    f16* Wc_ws  = (f16*)(ws + 786432);           // 128 KB f16 Wc  [p][r]

    proj_kernel<<<dim3(448), 256, 0, stream>>>(hs, Wqkv, bqkv, Wc, q_ws, k_ws, vT_ws, Wc_ws);
    attn_main<<<dim3(512), 512, 0, stream>>>(q_ws, k_ws, vT_ws, Wc_ws, out);
}

// Round 2
// 101.208 us; speedup vs baseline: 2.4658x; 2.4658x over previous
//
#include <hip/hip_runtime.h>
#include <hip/hip_bf16.h>
#include <math.h>

typedef __bf16 bf16;
typedef _Float16 f16;
typedef __attribute__((ext_vector_type(8))) __bf16 bf16x8;
typedef __attribute__((ext_vector_type(8))) _Float16 f16x8;
typedef __attribute__((ext_vector_type(4))) _Float16 f16x4;
typedef __attribute__((ext_vector_type(4))) float floatx4;

__device__ __forceinline__ void split8(floatx4 a0, floatx4 a1, bf16x8& hi, bf16x8& lo) {
#pragma unroll
    for (int t = 0; t < 4; t++) {
        float v0 = a0[t], v1 = a1[t];
        bf16 h0 = (bf16)v0, h1 = (bf16)v1;
        hi[t] = h0;     lo[t] = (bf16)(v0 - (float)h0);
        hi[t + 4] = h1; lo[t + 4] = (bf16)(v1 - (float)h1);
    }
}

// ---------------- projection: qkv = hs @ Wqkv^T + bqkv (fp32-accurate via bf16 hi/lo split) ----------------
// blocks 0..383: one 16x16 tile per wave -> q f16 [b*s][r], k f16 [b*l][r], vT f16 [b][p][l]
// blocks 384..447: Wc fp32 -> f16 copy (for the attn B-frag build)
__global__ __launch_bounds__(256, 4)
void proj_kernel(const float* __restrict__ hs, const float* __restrict__ Wq,
                 const float* __restrict__ bq, const float* __restrict__ Wc,
                 f16* __restrict__ q_ws, f16* __restrict__ k_ws,
                 f16* __restrict__ vT_ws, f16* __restrict__ Wc_ws)
{
    const int tid = threadIdx.x;
    if (blockIdx.x >= 384) {           // Wc fp32 -> f16
        const int base = (blockIdx.x - 384) * 1024 + tid * 4;
        floatx4 w = *(const floatx4*)(Wc + base);
        f16x4 h;
        h.x = (f16)w.x; h.y = (f16)w.y; h.z = (f16)w.z; h.w = (f16)w.w;
        *(f16x4*)(Wc_ws + base) = h;
        return;
    }
    const int wv = tid >> 6, lane = tid & 63;
    const int quad = lane >> 4, lcol = lane & 15;
    const int wt = blockIdx.x * 4 + wv;          // 0..1535: 32 row-tiles x 48 col-tiles
    const int rt = wt / 48, ct = wt - rt * 48;
    const int row0 = rt * 16, col0 = ct * 16;

    const float* arow = hs + (row0 + lcol) * 256;   // A: m = lcol (bs-row)
    const float* brow = Wq + (col0 + lcol) * 256;   // B: n = lcol (out-col), torch [out,in]

    floatx4 acc = {0.f, 0.f, 0.f, 0.f};
#pragma unroll
    for (int ks = 0; ks < 8; ks++) {
        const int h = ks * 32 + quad * 8;
        floatx4 a0 = *(const floatx4*)(arow + h);
        floatx4 a1 = *(const floatx4*)(arow + h + 4);
        floatx4 b0 = *(const floatx4*)(brow + h);
        floatx4 b1 = *(const floatx4*)(brow + h + 4);
        bf16x8 ahi, alo, bhi, blo;
        split8(a0, a1, ahi, alo);
        split8(b0, b1, bhi, blo);
        acc = __builtin_amdgcn_mfma_f32_16x16x32_bf16(ahi, bhi, acc, 0, 0, 0);
        acc = __builtin_amdgcn_mfma_f32_16x16x32_bf16(ahi, blo, acc, 0, 0, 0);
        acc = __builtin_amdgcn_mfma_f32_16x16x32_bf16(alo, bhi, acc, 0, 0, 0);
    }
    const float bias = bq[col0 + lcol];
    const int col = col0 + lcol, seg = col0 >> 8, jj = col & 255;
#pragma unroll
    for (int r = 0; r < 4; r++) {                   // C: row = quad*4 + r, col = lcol
        const int row = row0 + quad * 4 + r;
        const float val = acc[r] + bias;
        if (seg == 0)      q_ws[row * 256 + jj] = (f16)val;
        else if (seg == 1) k_ws[row * 256 + jj] = (f16)val;
        else               vT_ws[(row >> 8) * 65536 + jj * 256 + (row & 255)] = (f16)val;
    }
}

// ---------------- fused scores + softmax(l) + PV, v3: occupancy-first, VGPR=128 ----------------
// grid 512 = b(2) x sg(64: 4 s each) x pt(4: 64 p each). 512 thr = 8 waves = 2 s-halves x 4 l-quarters.
// LDS: ONLY Wc tile (32 KB, XOR-swizzled) + 8 KB merge buffers => ~41 KB.
// __launch_bounds__(512, 2): on this toolchain the observed VGPR cap for B=512 is 256/arg —
//   arg=4 gave VGPR=64 -> acc[4][4] spilled -> 890 MB scratch traffic, 185 us (R1 disaster).
//   arg=2 caps at 128 (v0 compiled to exactly 128 with MORE live state). VGPR=128 + 41 KB LDS
//   => 2 blocks/CU = 16 waves/CU, double the old kernel's residency.
// K fragments read straight from global: K is 256 KB f16 total, L2-resident.
// scores D[m=l, n=p]: A-frag = K (global), B-frag = q*Wc built in registers (pk_mul). No barriers in
// the main loop. P = exp(scores) in f32 (scores ~ N(0,1); bc cancels in softmax over l).
// PV + denominator fully in registers: acc holds P at (l = i*16+quad*4+t, p = j*16+lcol), vT is [p][l]
// -> per-lane FMAs + 2-step shfl_xor(16,32) butterfly over the quad bits. One LDS merge at the end.
__global__ __launch_bounds__(512, 2)
void attn_main(const f16* __restrict__ qw, const f16* __restrict__ kw,
               const f16* __restrict__ vT, const f16* __restrict__ Wc16,
               float* __restrict__ out)
{
    __shared__ f16 Wlds[64 * 256];      // 32768 B, XOR-swizzled (chunk c stores global chunk c^(row&7))
    __shared__ float obuf[4][4][64];    //  4096 B: [lq][s-slot][p]
    __shared__ float sbuf[4][4][64];    //  4096 B

    const int bid = blockIdx.x;
    const int pt = bid & 3;
    const int sg = (bid >> 2) & 63;
    const int b  = bid >> 8;
    const int p0 = pt * 64;
    const int tid  = threadIdx.x;
    const int wv   = tid >> 6;
    const int lane = tid & 63;
    const int quad = lane >> 4, lcol = lane & 15;
    const int lq = wv & 3, sh = wv >> 2;
    const int l0w = lq * 64;

    const f16* kbase = kw + b * 65536;
    const f16* vbase = vT + b * 65536;

    // ---- stage Wc tile [64 p][256 r] once, swizzled: 2048 16-B chunks / 512 thr = 4 iters ----
#pragma unroll
    for (int it = 0; it < 4; it++) {
        const int id = tid + it * 512;
        const int r = id >> 5, c = id & 31;
        const int csrc = c ^ (r & 7);
        uint4 d = *(const uint4*)(Wc16 + (p0 + r) * 256 + csrc * 8);
        *(uint4*)(Wlds + r * 256 + c * 8) = d;
    }
    __syncthreads();

    float osum[2][4], ssum[2][4];

#pragma unroll
    for (int sl = 0; sl < 2; sl++) {
        const int s = sg * 4 + sh * 2 + sl;
        const f16* qrow = qw + (b * 256 + s) * 256;

        floatx4 acc[4][4];
#pragma unroll
        for (int i = 0; i < 4; i++)
#pragma unroll
            for (int j = 0; j < 4; j++)
                acc[i][j] = (floatx4){0.f, 0.f, 0.f, 0.f};

#pragma unroll
        for (int kk = 0; kk < 8; kk++) {
            const int rb = kk * 32 + quad * 8;
            f16x8 qv = *(const f16x8*)(qrow + rb);
            f16x8 kf[4];
#pragma unroll
            for (int i = 0; i < 4; i++)    // A-frag from GLOBAL (L2-hot): m = lcol -> l-row
                kf[i] = *(const f16x8*)(kbase + (l0w + i * 16 + lcol) * 256 + rb);
#pragma unroll
            for (int j = 0; j < 4; j++) {  // B-frag: n = lcol -> p-row; built in regs (pk_mul)
                f16x8 w8 = *(const f16x8*)(Wlds + (j * 16 + lcol) * 256 +
                                           (((kk * 4 + quad) ^ (lcol & 7)) << 3));
                f16x8 bfr = w8 * qv;
#pragma unroll
                for (int i = 0; i < 4; i++)
                    acc[i][j] = __builtin_amdgcn_mfma_f32_16x16x32_f16(kf[i], bfr, acc[i][j], 0, 0, 0);
            }
        }

        // ---- in-register epilogue: P = exp(acc) in f32; osum/ssum per-lane, butterfly over quad ----
        float os[4] = {0.f, 0.f, 0.f, 0.f}, ss[4] = {0.f, 0.f, 0.f, 0.f};
#pragma unroll
        for (int i = 0; i < 4; i++) {
#pragma unroll
            for (int j = 0; j < 4; j++) {
                // v at (l = l0w+i*16+quad*4+t, p = p0+j*16+lcol): f16x4 contiguous in l
                f16x4 vf = *(const f16x4*)(vbase + (p0 + j * 16 + lcol) * 256 + l0w + i * 16 + quad * 4);
#pragma unroll
                for (int t = 0; t < 4; t++) {
                    const float P = __expf(acc[i][j][t]);
                    os[j] = fmaf(P, (float)vf[t], os[j]);
                    ss[j] += P;
                }
            }
        }
#pragma unroll
        for (int j = 0; j < 4; j++) {      // sum the 4 quad groups (lanes ^16, ^32)
            os[j] += __shfl_xor(os[j], 16);
            os[j] += __shfl_xor(os[j], 32);
            ss[j] += __shfl_xor(ss[j], 16);
            ss[j] += __shfl_xor(ss[j], 32);
            osum[sl][j] = os[j];
            ssum[sl][j] = ss[j];
        }
    }

    // ---- single cross-wave merge over lq ----
    if (quad == 0) {
#pragma unroll
        for (int sl = 0; sl < 2; sl++)
#pragma unroll
            for (int j = 0; j < 4; j++) {
                obuf[lq][sh * 2 + sl][j * 16 + lcol] = osum[sl][j];
                sbuf[lq][sh * 2 + sl][j * 16 + lcol] = ssum[sl][j];
            }
    }
    __syncthreads();

    if (tid < 256) {
        const int slot = tid >> 6, p = tid & 63;
        const float O = obuf[0][slot][p] + obuf[1][slot][p] + obuf[2][slot][p] + obuf[3][slot][p];
        const float S = sbuf[0][slot][p] + sbuf[1][slot][p] + sbuf[2][slot][p] + sbuf[3][slot][p];
        out[(b * 256 + sg * 4 + slot) * 256 + p0 + p] = O / S;
    }
}

extern "C" void kernel_launch(void* const* d_in, const int* in_sizes, int n_in,
                              void* d_out, int out_size, void* d_ws, size_t ws_size,
                              hipStream_t stream) {
    const float* hs   = (const float*)d_in[0];  // [2,256,256]
    const float* Wqkv = (const float*)d_in[1];  // [768,256]
    const float* bqkv = (const float*)d_in[2];  // [768]
    const float* Wc   = (const float*)d_in[3];  // [256,256]
    // d_in[4] (bc) cancels in softmax over l -> unused.
    float* out = (float*)d_out;

    char* ws = (char*)d_ws;
    f16* q_ws   = (f16*)ws;                      // 256 KB f16 q   [b*s][r]
    f16* k_ws   = (f16*)(ws + 262144);           // 256 KB f16 k   [b*l][r]
    f16* vT_ws  = (f16*)(ws + 524288);           // 256 KB f16 vT  [b][p][l]
    f16* Wc_ws  = (f16*)(ws + 786432);           // 128 KB f16 Wc  [p][r]

    proj_kernel<<<dim3(448), 256, 0, stream>>>(hs, Wqkv, bqkv, Wc, q_ws, k_ws, vT_ws, Wc_ws);
    attn_main<<<dim3(512), 512, 0, stream>>>(q_ws, k_ws, vT_ws, Wc_ws, out);
}